// Round 2
// baseline (113.644 us; speedup 1.0000x reference)
//
#include <hip/hip_runtime.h>
#include <math.h>

#define HID 2048
#define KQ (HID / 4)      // 512 float4 per HID-length row
#define MAXLEN 128
#define VOCAB 32000

__device__ __forceinline__ float wave_sum(float v) {
    #pragma unroll
    for (int m = 1; m < 64; m <<= 1) v += __shfl_xor(v, m, 64);
    return v;
}

__device__ __forceinline__ float dot4(const float4 a, const float4 b) {
    return a.x * b.x + a.y * b.y + a.z * b.z + a.w * b.w;
}

// ---- RNN cell: out[r] = tanh(W1[r]·x1 + W2[r]·x2 + b1[r] + b2[r]); wave per row ----
// if tok != nullptr, x1 is an embedding table indexed by tok[0]
__global__ void rnn_cell_kernel(const float* __restrict__ W1, const float* __restrict__ x1,
                                const int* __restrict__ tok,
                                const float* __restrict__ W2, const float* __restrict__ x2,
                                const float* __restrict__ b1, const float* __restrict__ b2,
                                float* __restrict__ out) {
    const int r = blockIdx.x * 4 + (threadIdx.x >> 6);
    const int lane = threadIdx.x & 63;
    const float4* xa = (const float4*)(tok ? x1 + (size_t)tok[0] * HID : x1);
    const float4* xb = (const float4*)x2;
    const float4* w1 = (const float4*)(W1 + (size_t)r * HID);
    const float4* w2 = (const float4*)(W2 + (size_t)r * HID);
    float p = 0.f;
    #pragma unroll 8
    for (int i = lane; i < KQ; i += 64) {
        p += dot4(w1[i], xa[i]);
        p += dot4(w2[i], xb[i]);
    }
    p = wave_sum(p);
    if (lane == 0) out[r] = tanhf(p + b1[r] + b2[r]);
}

// ---- concat matvec: out[r] = act(W[r,0:H]·emb_row + W[r,H:2H]·xb + b[r]); wave per row ----
template<int ACT>   // 0 = none, 2 = relu
__global__ void concat_mv_kernel(const float* __restrict__ W,
                                 const float* __restrict__ emb, const int* __restrict__ tok,
                                 const float* __restrict__ xb,
                                 const float* __restrict__ b,
                                 float* __restrict__ out) {
    const int r = blockIdx.x * 4 + (threadIdx.x >> 6);
    const int lane = threadIdx.x & 63;
    const float4* xa = (const float4*)(emb + (size_t)tok[0] * HID);
    const float4* xv = (const float4*)xb;
    const float4* w  = (const float4*)(W + (size_t)r * 2 * HID);
    float p = 0.f;
    #pragma unroll 8
    for (int i = lane; i < KQ; i += 64) {
        p += dot4(w[i], xa[i]);
        p += dot4(w[i + KQ], xv[i]);
    }
    p = wave_sum(p);
    if (lane == 0) {
        p += b[r];
        if (ACT == 2) p = fmaxf(p, 0.f);
        out[r] = p;
    }
}

// ---- fused softmax(128) + apply: out[j] = sum_l softmax(AL)[l] * enc[l][j] ----
__global__ void softmax_apply_kernel(const float* __restrict__ AL,
                                     const float* __restrict__ enc,
                                     float* __restrict__ out) {
    __shared__ float sAL[MAXLEN];
    __shared__ float wts[MAXLEN];
    const int t = threadIdx.x;
    if (t < MAXLEN) sAL[t] = AL[t];
    __syncthreads();
    // redundant per-thread softmax stats over 128 values (deterministic, cheap)
    float m = sAL[0];
    for (int l = 1; l < MAXLEN; ++l) m = fmaxf(m, sAL[l]);
    float s = 0.f;
    for (int l = 0; l < MAXLEN; ++l) s += expf(sAL[l] - m);
    if (t < MAXLEN) wts[t] = expf(sAL[t] - m) / s;
    __syncthreads();
    const int j = blockIdx.x * blockDim.x + t;
    float acc = 0.f;
    #pragma unroll 4
    for (int l = 0; l < MAXLEN; ++l) acc += wts[l] * enc[(size_t)l * HID + j];
    out[j] = acc;
}

// ---- big matvec + partial sum-of-exp: out[r] = out_W[r]·x + b[r]; wave per row ----
// logits are bounded (|logit| <= ||W row||*||tanh vec|| ~ 41) so exp() without
// max-subtraction is safe in f32; partials are combined in finalize.
__global__ void bigmv_kernel(const float* __restrict__ W, const float* __restrict__ x,
                             const float* __restrict__ b, float* __restrict__ out,
                             float* __restrict__ partial) {
    const int r = blockIdx.x * 4 + (threadIdx.x >> 6);
    const int lane = threadIdx.x & 63;
    const float4* xv = (const float4*)x;
    const float4* w  = (const float4*)(W + (size_t)r * HID);
    float p = 0.f;
    #pragma unroll 8
    for (int i = lane; i < KQ; i += 64) p += dot4(w[i], xv[i]);
    p = wave_sum(p);
    if (lane == 0) {
        p += b[r];
        out[r] = p;
        atomicAdd(&partial[r & 255], expf(p));   // 125 adds/slot, hidden under BW
    }
}

// ---- finalize: every block reduces the same 256 partials (identical order ->
// identical lg), then applies out[i] -= log(sum) to its 256-element chunk ----
__global__ void finalize_kernel(const float* __restrict__ partial, float* __restrict__ out) {
    __shared__ float red[4];
    const int t = threadIdx.x, lane = t & 63, w = t >> 6;
    float v = partial[t];
    v = wave_sum(v);
    if (lane == 0) red[w] = v;
    __syncthreads();
    const float lg = logf(red[0] + red[1] + red[2] + red[3]);
    const int i = blockIdx.x * 256 + t;   // 125 * 256 == 32000 exactly
    out[i] -= lg;
}

extern "C" void kernel_launch(void* const* d_in, const int* in_sizes, int n_in,
                              void* d_out, int out_size, void* d_ws, size_t ws_size,
                              hipStream_t stream) {
    const int*   tok    = (const int*)  d_in[0];
    const float* hidden = (const float*)d_in[1];
    const float* enc    = (const float*)d_in[2];
    const float* emb    = (const float*)d_in[3];
    const float* attn_W = (const float*)d_in[4];
    const float* attn_b = (const float*)d_in[5];
    const float* comb_W = (const float*)d_in[6];
    const float* comb_b = (const float*)d_in[7];
    const float* W_ih   = (const float*)d_in[8];
    const float* W_hh   = (const float*)d_in[9];
    const float* b_ih   = (const float*)d_in[10];
    const float* b_hh   = (const float*)d_in[11];
    const float* out_W  = (const float*)d_in[12];
    const float* out_b  = (const float*)d_in[13];
    float* out = (float*)d_out;

    float* ws = (float*)d_ws;
    float* H1 = ws;          // [2048] hidden after rnn step 1
    float* AL = ws + 2048;   // [128]  attn logits
    float* AA = ws + 2176;   // [2048] attn applied (16B aligned)
    float* O  = ws + 4224;   // [2048] combined + relu
    float* OH = ws + 6272;   // [2048] hidden after rnn step 2
    float* P  = ws + 8320;   // [256]  partial sum-of-exp slots

    // 1. H1 = tanh(W_ih·emb[tok] + W_hh·hidden + b_ih + b_hh)
    rnn_cell_kernel<<<HID / 4, 256, 0, stream>>>(W_ih, emb, tok, W_hh, hidden, b_ih, b_hh, H1);
    // 2. AL = attn_W·[emb[tok]; H1] + attn_b
    concat_mv_kernel<0><<<MAXLEN / 4, 256, 0, stream>>>(attn_W, emb, tok, H1, attn_b, AL);
    // 3. AA = softmax(AL)·enc
    softmax_apply_kernel<<<HID / 256, 256, 0, stream>>>(AL, enc, AA);
    // 4. O = relu(comb_W·[emb[tok]; AA] + comb_b)
    concat_mv_kernel<2><<<HID / 4, 256, 0, stream>>>(comb_W, emb, tok, AA, comb_b, O);
    // 5. OH = tanh(W_ih·O + W_hh·H1 + b_ih + b_hh)
    rnn_cell_kernel<<<HID / 4, 256, 0, stream>>>(W_ih, O, nullptr, W_hh, H1, b_ih, b_hh, OH);
    // 6. zero the exp partials (ws is NOT re-poisoned between replays)
    hipMemsetAsync(P, 0, 256 * sizeof(float), stream);
    // 7. out = out_W·OH + out_b, accumulating partial sum(exp(logit))
    bigmv_kernel<<<VOCAB / 4, 256, 0, stream>>>(out_W, OH, out_b, out, P);
    // 8. out[i] -= log(sum(exp))
    finalize_kernel<<<VOCAB / 256, 256, 0, stream>>>(P, out);
}

// Round 3
// 111.072 us; speedup vs baseline: 1.0232x; 1.0232x over previous
//
#include <hip/hip_runtime.h>
#include <math.h>

#define HID 2048
#define KQ (HID / 4)      // 512 float4 per HID-length row
#define MAXLEN 128
#define VOCAB 32000

__device__ __forceinline__ float wave_sum(float v) {
    #pragma unroll
    for (int m = 1; m < 64; m <<= 1) v += __shfl_xor(v, m, 64);
    return v;
}

__device__ __forceinline__ float dot4(const float4 a, const float4 b) {
    return a.x * b.x + a.y * b.y + a.z * b.z + a.w * b.w;
}

// block-level reduce for 256 threads (4 waves); result valid on thread 0
__device__ __forceinline__ float block_sum256(float v) {
    __shared__ float s[4];
    v = wave_sum(v);
    const int lane = threadIdx.x & 63, w = threadIdx.x >> 6;
    if (lane == 0) s[w] = v;
    __syncthreads();
    return s[0] + s[1] + s[2] + s[3];   // all threads compute same value
}

// ---- RNN cell, block per row: out[r] = tanh(W1[r]·x1 + W2[r]·x2 + b1[r] + b2[r]) ----
// if tok != nullptr, x1 is an embedding table indexed by tok[0].
// block 0 additionally zeroes the 256 exp-partial slots (replaces a memset node).
__global__ __launch_bounds__(256)
void rnn_cell_kernel(const float* __restrict__ W1, const float* __restrict__ x1,
                     const int* __restrict__ tok,
                     const float* __restrict__ W2, const float* __restrict__ x2,
                     const float* __restrict__ b1, const float* __restrict__ b2,
                     float* __restrict__ out, float* __restrict__ zeroP) {
    const int r = blockIdx.x;
    const int t = threadIdx.x;
    if (zeroP && r == 0) zeroP[t] = 0.f;
    const float4* xa = (const float4*)(tok ? x1 + (size_t)tok[0] * HID : x1);
    const float4* xb = (const float4*)x2;
    const float4* w1 = (const float4*)(W1 + (size_t)r * HID);
    const float4* w2 = (const float4*)(W2 + (size_t)r * HID);
    float p = dot4(w1[t], xa[t]) + dot4(w1[t + 256], xa[t + 256])
            + dot4(w2[t], xb[t]) + dot4(w2[t + 256], xb[t + 256]);
    p = block_sum256(p);
    if (t == 0) out[r] = tanhf(p + b1[r] + b2[r]);
}

// ---- concat matvec, block per row: out[r] = act(W[r,0:H]·emb_row + W[r,H:2H]·xb + b[r]) ----
template<int ACT>   // 0 = none, 2 = relu
__global__ __launch_bounds__(256)
void concat_mv_kernel(const float* __restrict__ W,
                      const float* __restrict__ emb, const int* __restrict__ tok,
                      const float* __restrict__ xb,
                      const float* __restrict__ b,
                      float* __restrict__ out) {
    const int r = blockIdx.x;
    const int t = threadIdx.x;
    const float4* xa = (const float4*)(emb + (size_t)tok[0] * HID);
    const float4* xv = (const float4*)xb;
    const float4* w  = (const float4*)(W + (size_t)r * 2 * HID);
    float p = dot4(w[t], xa[t]) + dot4(w[t + 256], xa[t + 256])
            + dot4(w[t + 512], xv[t]) + dot4(w[t + 768], xv[t + 256]);
    p = block_sum256(p);
    if (t == 0) {
        p += b[r];
        if (ACT == 2) p = fmaxf(p, 0.f);
        out[r] = p;
    }
}

// ---- fused softmax(128) + apply: out[j] = sum_l softmax(AL)[l] * enc[l][j] ----
__global__ __launch_bounds__(256)
void softmax_apply_kernel(const float* __restrict__ AL,
                          const float* __restrict__ enc,
                          float* __restrict__ out) {
    __shared__ float sAL[MAXLEN];
    __shared__ float wts[MAXLEN];
    const int t = threadIdx.x;
    if (t < MAXLEN) sAL[t] = AL[t];
    __syncthreads();
    // redundant per-thread softmax stats over 128 values (deterministic, cheap)
    float m = sAL[0];
    for (int l = 1; l < MAXLEN; ++l) m = fmaxf(m, sAL[l]);
    float s = 0.f;
    for (int l = 0; l < MAXLEN; ++l) s += expf(sAL[l] - m);
    if (t < MAXLEN) wts[t] = expf(sAL[t] - m) / s;
    __syncthreads();
    const int j = blockIdx.x * blockDim.x + t;
    float acc = 0.f;
    #pragma unroll 4
    for (int l = 0; l < MAXLEN; ++l) acc += wts[l] * enc[(size_t)l * HID + j];
    out[j] = acc;
}

// ---- big matvec + partial sum-of-exp, wave per row ----
// |logit| <= ||W row||*||tanh vec|| ~ 41, so exp() without max-subtraction is
// safe in f32 (exp(41)*32000 ~ 2e22 << f32 max).
__global__ __launch_bounds__(256)
void bigmv_kernel(const float* __restrict__ W, const float* __restrict__ x,
                  const float* __restrict__ b, float* __restrict__ out,
                  float* __restrict__ partial) {
    const int r = blockIdx.x * 4 + (threadIdx.x >> 6);
    const int lane = threadIdx.x & 63;
    const float4* xv = (const float4*)x;
    const float4* w  = (const float4*)(W + (size_t)r * HID);
    float p = 0.f;
    #pragma unroll 8
    for (int i = lane; i < KQ; i += 64) p += dot4(w[i], xv[i]);
    p = wave_sum(p);
    if (lane == 0) {
        p += b[r];
        out[r] = p;
        atomicAdd(&partial[r & 255], expf(p));   // 125 adds/slot, hidden under BW
    }
}

// ---- finalize: every block reduces the same 256 partials (identical order ->
// identical lg), then applies out[i] -= log(sum) to its 256-element chunk ----
__global__ __launch_bounds__(256)
void finalize_kernel(const float* __restrict__ partial, float* __restrict__ out) {
    const int t = threadIdx.x;
    float lg = logf(block_sum256(partial[t]));
    const int i = blockIdx.x * 256 + t;   // 125 * 256 == 32000 exactly
    out[i] -= lg;
}

extern "C" void kernel_launch(void* const* d_in, const int* in_sizes, int n_in,
                              void* d_out, int out_size, void* d_ws, size_t ws_size,
                              hipStream_t stream) {
    const int*   tok    = (const int*)  d_in[0];
    const float* hidden = (const float*)d_in[1];
    const float* enc    = (const float*)d_in[2];
    const float* emb    = (const float*)d_in[3];
    const float* attn_W = (const float*)d_in[4];
    const float* attn_b = (const float*)d_in[5];
    const float* comb_W = (const float*)d_in[6];
    const float* comb_b = (const float*)d_in[7];
    const float* W_ih   = (const float*)d_in[8];
    const float* W_hh   = (const float*)d_in[9];
    const float* b_ih   = (const float*)d_in[10];
    const float* b_hh   = (const float*)d_in[11];
    const float* out_W  = (const float*)d_in[12];
    const float* out_b  = (const float*)d_in[13];
    float* out = (float*)d_out;

    float* ws = (float*)d_ws;
    float* H1 = ws;          // [2048] hidden after rnn step 1
    float* AL = ws + 2048;   // [128]  attn logits
    float* AA = ws + 2176;   // [2048] attn applied (16B aligned)
    float* O  = ws + 4224;   // [2048] combined + relu
    float* OH = ws + 6272;   // [2048] hidden after rnn step 2
    float* P  = ws + 8320;   // [256]  partial sum-of-exp slots

    // 1. H1 = tanh(W_ih·emb[tok] + W_hh·hidden + ...); block 0 zeroes P
    rnn_cell_kernel<<<HID, 256, 0, stream>>>(W_ih, emb, tok, W_hh, hidden, b_ih, b_hh, H1, P);
    // 2. AL = attn_W·[emb[tok]; H1] + attn_b
    concat_mv_kernel<0><<<MAXLEN, 256, 0, stream>>>(attn_W, emb, tok, H1, attn_b, AL);
    // 3. AA = softmax(AL)·enc
    softmax_apply_kernel<<<HID / 256, 256, 0, stream>>>(AL, enc, AA);
    // 4. O = relu(comb_W·[emb[tok]; AA] + comb_b)
    concat_mv_kernel<2><<<HID, 256, 0, stream>>>(comb_W, emb, tok, AA, comb_b, O);
    // 5. OH = tanh(W_ih·O + W_hh·H1 + ...)
    rnn_cell_kernel<<<HID, 256, 0, stream>>>(W_ih, O, nullptr, W_hh, H1, b_ih, b_hh, OH, nullptr);
    // 6. out = out_W·OH + out_b, accumulating partial sum(exp(logit)) into P
    bigmv_kernel<<<VOCAB / 4, 256, 0, stream>>>(out_W, OH, out_b, out, P);
    // 7. out[i] -= log(sum(exp))
    finalize_kernel<<<VOCAB / 256, 256, 0, stream>>>(P, out);
}